// Round 11
// baseline (147.302 us; speedup 1.0000x reference)
//
#include <hip/hip_runtime.h>
#include <hip/hip_bf16.h>
#include <math.h>

#define N2 147456
#define CC 128
#define TILES 2304   // N2/64

// workspace float offsets
#define WS_VACC  0      // [2][32][32]
#define WS_S     2048   // [2][32]
#define WS_FS    2112   // [2][128]  FiLM scale (1+scale)
#define WS_SH    2368   // [2][128]  FiLM shift
#define WS_UPACK 2624   // [2][8][64][8] bf16 = 16 KB = 4096 floats (packed ufrag)
#define WS_B2P   6720   // [2][128]  b2' = bo*fs + shift

typedef __attribute__((ext_vector_type(8))) __bf16 bf16x8;
typedef __attribute__((ext_vector_type(4))) __bf16 bf16x4;
typedef __attribute__((ext_vector_type(4))) float f32x4;
typedef __attribute__((ext_vector_type(4))) short short4v;

#define MFMA16(a_, b_, c_) __builtin_amdgcn_mfma_f32_16x16x32_bf16((a_), (b_), (c_), 0, 0, 0)

// 16x16x16 bf16 MFMA (K=16): carried-forward shape on gfx950 (ISA §10).
static __device__ inline f32x4 mfma_k16(bf16x4 a, bf16x4 b, f32x4 c) {
#if __has_builtin(__builtin_amdgcn_mfma_f32_16x16x16_bf16)
    return __builtin_amdgcn_mfma_f32_16x16x16_bf16(a, b, c, 0, 0, 0);
#elif __has_builtin(__builtin_amdgcn_mfma_f32_16x16x16bf16_1k)
    return __builtin_amdgcn_mfma_f32_16x16x16bf16_1k(
        __builtin_bit_cast(short4v, a), __builtin_bit_cast(short4v, b), c, 0, 0, 0);
#else
    asm("v_mfma_f32_16x16x16_bf16 %0, %1, %2, %0" : "+v"(c) : "v"(a), "v"(b));
    return c;
#endif
}

// ---------------------------------------------------------------------------
// k0: zero accumulators (blocks 1..9) + FiLM time-MLP (block 0).
// ---------------------------------------------------------------------------
__global__ __launch_bounds__(256) void k0_init(
    const float* __restrict__ r3t,
    const float* __restrict__ W1, const float* __restrict__ b1,
    const float* __restrict__ W2, const float* __restrict__ b2,
    float* __restrict__ ws)
{
    const int t = threadIdx.x, bx = blockIdx.x;
    if (bx > 0) {
        const int i = (bx - 1) * 256 + t;
        if (i < 2112) ws[i] = 0.0f;
        return;
    }
    __shared__ float h[2][128];
    {
        const int b = t >> 7, j = t & 127;
        const float x = r3t[b] * W1[j] + b1[j];
        h[b][j] = 0.5f * x * (1.0f + erff(x * 0.7071067811865475f));
    }
    __syncthreads();
    const int j2 = t;
    float acc0 = b2[j2], acc1 = b2[j2];
    for (int k = 0; k < 128; ++k) {
        const float w2 = W2[k * 256 + j2];
        acc0 += h[0][k] * w2;
        acc1 += h[1][k] * w2;
    }
    if (j2 < 128) {
        ws[WS_FS + j2]       = 1.0f + acc0;
        ws[WS_FS + 128 + j2] = 1.0f + acc1;
    } else {
        ws[WS_SH + (j2 - 128)]       = acc0;
        ws[WS_SH + 128 + (j2 - 128)] = acc1;
    }
}

// ---------------------------------------------------------------------------
// k1: BARRIER-FREE accumulation pass (round-8, proven -6.5us). Unchanged.
// ---------------------------------------------------------------------------
__global__ __launch_bounds__(256, 3) void k1_accum(
    const float* __restrict__ P, const int* __restrict__ mask,
    const float* __restrict__ Wg, const float* __restrict__ bg,
    const float* __restrict__ Wv, const float* __restrict__ bv,
    float* __restrict__ ws)
{
    __shared__ float red[4][1024];   // per-wave V' image [d*32+e]
    __shared__ float red_s[4][32];   // per-wave S image

    const int t  = threadIdx.x;
    const int b  = blockIdx.y;
    const int w  = t >> 6;
    const int l  = t & 63;
    const int lr = l & 15;
    const int lg = l >> 4;

    bf16x8 wfrag[2][2][4];
    #pragma unroll
    for (int nt = 0; nt < 2; ++nt)
      #pragma unroll
      for (int ks = 0; ks < 4; ++ks) {
        const int base = (ks * 32 + 8 * lg) * 32 + nt * 16 + lr;
        bf16x8 f0, f1;
        #pragma unroll
        for (int i = 0; i < 8; ++i) {
            f0[i] = (__bf16)Wg[base + i * 32];
            f1[i] = (__bf16)Wv[base + i * 32];
        }
        wfrag[0][nt][ks] = f0;
        wfrag[1][nt][ks] = f1;
      }
    const float bgv[2] = { bg[lr], bg[lr + 16] };
    const float bvv[2] = { bv[lr], bv[lr + 16] };

    f32x4 vq00 = {0,0,0,0}, vq01 = {0,0,0,0}, vq10 = {0,0,0,0}, vq11 = {0,0,0,0};
    float s0 = 0.f, s1 = 0.f;   // lane-partial S for d=lr / d=lr+16

    const float* Pb = P + (size_t)b * N2 * CC;
    const int*   mb = mask + (size_t)b * N2;

    for (int tile = blockIdx.x; tile < TILES; tile += gridDim.x) {
        const int row0 = tile * 64 + w * 16;
        const float* prow = Pb + (size_t)(row0 + lr) * CC + 8 * lg;

        bf16x8 afrag[4];
        #pragma unroll
        for (int ks = 0; ks < 4; ++ks) {
            const float4 a0 = *(const float4*)(prow + ks * 32);
            const float4 a1 = *(const float4*)(prow + ks * 32 + 4);
            bf16x8 f;
            f[0] = (__bf16)a0.x; f[1] = (__bf16)a0.y; f[2] = (__bf16)a0.z; f[3] = (__bf16)a0.w;
            f[4] = (__bf16)a1.x; f[5] = (__bf16)a1.y; f[6] = (__bf16)a1.z; f[7] = (__bf16)a1.w;
            afrag[ks] = f;
        }

        f32x4 facc0 = {0,0,0,0}, facc1 = {0,0,0,0}, gacc0 = {0,0,0,0}, gacc1 = {0,0,0,0};
        #pragma unroll
        for (int ks = 0; ks < 4; ++ks) {
            facc0 = MFMA16(afrag[ks], wfrag[0][0][ks], facc0);
            facc1 = MFMA16(afrag[ks], wfrag[0][1][ks], facc1);
            gacc0 = MFMA16(afrag[ks], wfrag[1][0][ks], gacc0);
            gacc1 = MFMA16(afrag[ks], wfrag[1][1][ks], gacc1);
        }

        const int4 mk4 = *(const int4*)&mb[row0 + lg * 4];
        const int mk[4] = { mk4.x, mk4.y, mk4.z, mk4.w };

        bf16x4 pe0, pe1, pg0, pg1;
        #pragma unroll
        for (int r = 0; r < 4; ++r) {
            pe0[r] = (__bf16)(mk[r] ? __expf(facc0[r] + bgv[0]) : 0.0f);
            pe1[r] = (__bf16)(mk[r] ? __expf(facc1[r] + bgv[1]) : 0.0f);
            pg0[r] = (__bf16)(gacc0[r] + bvv[0]);
            pg1[r] = (__bf16)(gacc1[r] + bvv[1]);
        }

        #pragma unroll
        for (int r = 0; r < 4; ++r) {
            s0 += (float)pe0[r];
            s1 += (float)pe1[r];
        }

        vq00 = mfma_k16(pe0, pg0, vq00);
        vq01 = mfma_k16(pe0, pg1, vq01);
        vq10 = mfma_k16(pe1, pg0, vq10);
        vq11 = mfma_k16(pe1, pg1, vq11);
    }

    s0 += __shfl_xor(s0, 16); s0 += __shfl_xor(s0, 32);
    s1 += __shfl_xor(s1, 16); s1 += __shfl_xor(s1, 32);

    #pragma unroll
    for (int r = 0; r < 4; ++r) {
        red[w][(     4 * lg + r) * 32 +      lr] = vq00[r];
        red[w][(     4 * lg + r) * 32 + 16 + lr] = vq01[r];
        red[w][(16 + 4 * lg + r) * 32 +      lr] = vq10[r];
        red[w][(16 + 4 * lg + r) * 32 + 16 + lr] = vq11[r];
    }
    if (lg == 0) { red_s[w][lr] = s0; red_s[w][16 + lr] = s1; }
    __syncthreads();

    #pragma unroll
    for (int i = 0; i < 4; ++i) {
        const int idx = t + i * 256;
        const float v = red[0][idx] + red[1][idx] + red[2][idx] + red[3][idx];
        atomicAdd(ws + WS_VACC + b * 1024 + idx, v);
    }
    if (t < 32) {
        const float sv = red_s[0][t] + red_s[1][t] + red_s[2][t] + red_s[3][t];
        atomicAdd(ws + WS_S + b * 32 + t, sv);
    }
}

// ---------------------------------------------------------------------------
// k2_mid: 2 blocks (one per batch). V-normalize, U' = V@Wo (fp32, staged Wo
// in LDS), scale by fs, write U' PRE-PACKED as bf16 MFMA A-frags + b2'.
// ---------------------------------------------------------------------------
__global__ __launch_bounds__(256) void k2_mid(
    const float* __restrict__ Wo, const float* __restrict__ bo,
    float* __restrict__ ws)
{
    __shared__ float V[1024];        // [d][e]
    __shared__ float wo[32][128];
    __shared__ float fs[128];
    const int t = threadIdx.x, b = blockIdx.x;

    if (t < 128) fs[t] = ws[WS_FS + b * 128 + t];
    #pragma unroll
    for (int i = 0; i < 4; ++i) {
        const int idx = t + i * 256;            // d*32+e
        const int d = idx >> 5;
        const float s = ws[WS_S + b * 32 + d];
        V[idx] = ws[WS_VACC + b * 1024 + idx] / (s * (1.0f + 1e-8f));
    }
    #pragma unroll
    for (int i = 0; i < 4; ++i) {
        const int j = t + i * 256;              // 1024 float4 = 4096 floats
        ((float4*)&wo[0][0])[j] = ((const float4*)Wo)[j];
    }
    __syncthreads();

    const int c = t & 127, dh = t >> 7;
    float wcol[32];
    #pragma unroll
    for (int e = 0; e < 32; ++e) wcol[e] = wo[e][c];
    const float fsc = fs[c];
    if (dh == 0) ws[WS_B2P + b * 128 + c] = bo[c] * fsc + ws[WS_SH + b * 128 + c];

    __bf16* dst = (__bf16*)(ws + WS_UPACK);
    #pragma unroll
    for (int dd = 0; dd < 16; ++dd) {
        const int d = dh * 16 + dd;
        float acc = 0.0f;
        #pragma unroll
        for (int e = 0; e < 32; ++e) acc += V[d * 32 + e] * wcol[e];
        acc *= fsc;
        // pack for lane l=(lg*16+lr): ufrag[nt][i] = U'[8*lg+i][nt*16+lr]
        const int lg = d >> 3, ii = d & 7, nt = c >> 4, lr = c & 15;
        dst[(((size_t)b * 8 + nt) * 64 + (lg * 16 + lr)) * 8 + ii] = (__bf16)acc;
    }
}

// ---------------------------------------------------------------------------
// k3: EXACT round-4/8 body. ONE change: __launch_bounds__(256,3) -> (256,4).
// The body needs 84 VGPR / 5 KB LDS -- it fits the 4-blocks/CU budget
// (cap 128 VGPR, 20 KB LDS) with 44 registers of slack. r3's spill at
// (256,4) was caused by the added a4[8]/p4v[8] arrays, not the bound.
// +33% resident waves to cover the load->cvt->MFMA->softmax->LDS->MFMA
// chain. Tripwires: VGPR must stay 84-128 (not 64), WRITE == 147456 KB.
// ---------------------------------------------------------------------------
__global__ __launch_bounds__(256, 4) void k3_out(
    const float* __restrict__ P,
    const float* __restrict__ Wd, const float* __restrict__ bd,
    const float* __restrict__ ws, float* __restrict__ out)
{
    __shared__ __bf16 h_t[64][40];   // [wave-row][d], stride 40 el = 16B-aligned

    const int t  = threadIdx.x;
    const int b  = blockIdx.y;
    const int w  = t >> 6, l = t & 63, lr = l & 15, lg = l >> 4;

    // packed U' frags: 8 x 16B loads
    bf16x8 ufrag[8];
    {
        const bf16x8* up = (const bf16x8*)(ws + WS_UPACK) + (size_t)b * 512 + l;
        #pragma unroll
        for (int nt = 0; nt < 8; ++nt) ufrag[nt] = up[nt * 64];
    }
    // b2' per c-tile
    float b2v[8][4];
    #pragma unroll
    for (int nt = 0; nt < 8; ++nt) {
        const float4 v = *(const float4*)(ws + WS_B2P + b * 128 + nt * 16 + lg * 4);
        b2v[nt][0] = v.x; b2v[nt][1] = v.y; b2v[nt][2] = v.z; b2v[nt][3] = v.w;
    }
    // Wd frags (L2-broadcast)
    bf16x8 wdfrag[2][4];
    #pragma unroll
    for (int nt = 0; nt < 2; ++nt)
      #pragma unroll
      for (int ks = 0; ks < 4; ++ks) {
        const int base = (ks * 32 + 8 * lg) * 32 + nt * 16 + lr;
        bf16x8 f;
        #pragma unroll
        for (int i = 0; i < 8; ++i) f[i] = (__bf16)Wd[base + i * 32];
        wdfrag[nt][ks] = f;
      }
    float bdv[8];
    #pragma unroll
    for (int r = 0; r < 4; ++r) {
        bdv[r]     = bd[lg * 4 + r];
        bdv[4 + r] = bd[16 + lg * 4 + r];
    }

    const float* Pb = P + (size_t)b * N2 * CC;
    float*       Ob = out + (size_t)b * N2 * CC;

    for (int tile = TILES - 1 - blockIdx.x; tile >= 0; tile -= gridDim.x) {
        const int row0 = tile * 64 + w * 16;
        const size_t rbase = (size_t)(row0 + lr) * CC;
        const float* prow = Pb + rbase + 8 * lg;

        bf16x8 afrag[4];
        #pragma unroll
        for (int ks = 0; ks < 4; ++ks) {
            const float4 a0 = *(const float4*)(prow + ks * 32);
            const float4 a1 = *(const float4*)(prow + ks * 32 + 4);
            bf16x8 f;
            f[0] = (__bf16)a0.x; f[1] = (__bf16)a0.y; f[2] = (__bf16)a0.z; f[3] = (__bf16)a0.w;
            f[4] = (__bf16)a1.x; f[5] = (__bf16)a1.y; f[6] = (__bf16)a1.z; f[7] = (__bf16)a1.w;
            afrag[ks] = f;
        }

        // T^T: lane holds row=row0+lr, d = {lg*4+r, 16+lg*4+r}
        f32x4 dacc0 = {0,0,0,0}, dacc1 = {0,0,0,0};
        #pragma unroll
        for (int ks = 0; ks < 4; ++ks) {
            dacc0 = MFMA16(wdfrag[0][ks], afrag[ks], dacc0);
            dacc1 = MFMA16(wdfrag[1][ks], afrag[ks], dacc1);
        }

        float v[8];
        #pragma unroll
        for (int r = 0; r < 4; ++r) {
            v[r]     = dacc0[r] + bdv[r];
            v[4 + r] = dacc1[r] + bdv[4 + r];
        }
        // softmax over d=32: 8 in-lane + lanes {l^16, l^32}
        float m = v[0];
        #pragma unroll
        for (int j = 1; j < 8; ++j) m = fmaxf(m, v[j]);
        m = fmaxf(m, __shfl_xor(m, 16));
        m = fmaxf(m, __shfl_xor(m, 32));
        float e[8], s = 0.f;
        #pragma unroll
        for (int j = 0; j < 8; ++j) { e[j] = __expf(v[j] - m); s += e[j]; }
        s += __shfl_xor(s, 16);
        s += __shfl_xor(s, 32);
        const float inv = 1.0f / s;

        bf16x4 h0, h1;
        #pragma unroll
        for (int r = 0; r < 4; ++r) {
            h0[r] = (__bf16)(e[r] * inv);
            h1[r] = (__bf16)(e[4 + r] * inv);
        }
        const int hrow = w * 16 + lr;
        *(bf16x4*)&h_t[hrow][lg * 4]      = h0;
        *(bf16x4*)&h_t[hrow][16 + lg * 4] = h1;
        // wave-private rows: whole-wave DS ordering, no barrier needed
        const bf16x8 hf = *(const bf16x8*)&h_t[hrow][8 * lg];

        // O^T per c-tile: lane -> row=row0+lr, c = nt*16 + lg*4 + {0..3}
        #pragma unroll
        for (int nt = 0; nt < 8; ++nt) {
            f32x4 ci;
            ci[0] = b2v[nt][0]; ci[1] = b2v[nt][1]; ci[2] = b2v[nt][2]; ci[3] = b2v[nt][3];
            const f32x4 oacc = MFMA16(ufrag[nt], hf, ci);
            const size_t off = rbase + nt * 16 + lg * 4;
            const float4 p4 = *(const float4*)(Pb + off);
            float4 o4;
            o4.x = p4.x + oacc[0]; o4.y = p4.y + oacc[1];
            o4.z = p4.z + oacc[2]; o4.w = p4.w + oacc[3];
            *(float4*)(Ob + off) = o4;
        }
    }
}

extern "C" void kernel_launch(void* const* d_in, const int* in_sizes, int n_in,
                              void* d_out, int out_size, void* d_ws, size_t ws_size,
                              hipStream_t stream) {
    const float* P   = (const float*)d_in[0];
    const int*   msk = (const int*)d_in[1];
    const float* r3t = (const float*)d_in[2];
    const float* Wg  = (const float*)d_in[3];
    const float* bg  = (const float*)d_in[4];
    const float* Wv  = (const float*)d_in[5];
    const float* bv  = (const float*)d_in[6];
    const float* Wd  = (const float*)d_in[7];
    const float* bd  = (const float*)d_in[8];
    const float* Wo  = (const float*)d_in[9];
    const float* bo  = (const float*)d_in[10];
    const float* W1  = (const float*)d_in[11];
    const float* b1  = (const float*)d_in[12];
    const float* W2  = (const float*)d_in[13];
    const float* b2  = (const float*)d_in[14];
    float* ws  = (float*)d_ws;
    float* out = (float*)d_out;

    hipLaunchKernelGGL(k0_init,  dim3(10),      dim3(256), 0, stream, r3t, W1, b1, W2, b2, ws);
    hipLaunchKernelGGL(k1_accum, dim3(384, 2),  dim3(256), 0, stream, P, msk, Wg, bg, Wv, bv, ws);
    hipLaunchKernelGGL(k2_mid,   dim3(2),       dim3(256), 0, stream, Wo, bo, ws);
    hipLaunchKernelGGL(k3_out,   dim3(768, 2),  dim3(256), 0, stream, P, Wd, bd, ws, out);
}

// Round 12
// 130.988 us; speedup vs baseline: 1.1245x; 1.1245x over previous
//
#include <hip/hip_runtime.h>
#include <hip/hip_bf16.h>
#include <math.h>

#define N2 147456
#define CC 128
#define TILES 2304   // N2/64

// workspace float offsets
#define WS_VACC  0      // [2][32][32]
#define WS_S     2048   // [2][32]
#define WS_FS    2112   // [2][128]  FiLM scale (1+scale)
#define WS_SH    2368   // [2][128]  FiLM shift
#define WS_UPACK 2624   // [2][8][64][8] bf16 = 16 KB = 4096 floats (packed ufrag)
#define WS_B2P   6720   // [2][128]  b2' = bo*fs + shift

typedef __attribute__((ext_vector_type(8))) __bf16 bf16x8;
typedef __attribute__((ext_vector_type(4))) __bf16 bf16x4;
typedef __attribute__((ext_vector_type(4))) float f32x4;
typedef __attribute__((ext_vector_type(4))) short short4v;

#define MFMA16(a_, b_, c_) __builtin_amdgcn_mfma_f32_16x16x32_bf16((a_), (b_), (c_), 0, 0, 0)

// 16x16x16 bf16 MFMA (K=16): carried-forward shape on gfx950 (ISA §10).
static __device__ inline f32x4 mfma_k16(bf16x4 a, bf16x4 b, f32x4 c) {
#if __has_builtin(__builtin_amdgcn_mfma_f32_16x16x16_bf16)
    return __builtin_amdgcn_mfma_f32_16x16x16_bf16(a, b, c, 0, 0, 0);
#elif __has_builtin(__builtin_amdgcn_mfma_f32_16x16x16bf16_1k)
    return __builtin_amdgcn_mfma_f32_16x16x16bf16_1k(
        __builtin_bit_cast(short4v, a), __builtin_bit_cast(short4v, b), c, 0, 0, 0);
#else
    asm("v_mfma_f32_16x16x16_bf16 %0, %1, %2, %0" : "+v"(c) : "v"(a), "v"(b));
    return c;
#endif
}

// ---------------------------------------------------------------------------
// k0: zero accumulators (blocks 1..9) + FiLM time-MLP (block 0).
// ---------------------------------------------------------------------------
__global__ __launch_bounds__(256) void k0_init(
    const float* __restrict__ r3t,
    const float* __restrict__ W1, const float* __restrict__ b1,
    const float* __restrict__ W2, const float* __restrict__ b2,
    float* __restrict__ ws)
{
    const int t = threadIdx.x, bx = blockIdx.x;
    if (bx > 0) {
        const int i = (bx - 1) * 256 + t;
        if (i < 2112) ws[i] = 0.0f;
        return;
    }
    __shared__ float h[2][128];
    {
        const int b = t >> 7, j = t & 127;
        const float x = r3t[b] * W1[j] + b1[j];
        h[b][j] = 0.5f * x * (1.0f + erff(x * 0.7071067811865475f));
    }
    __syncthreads();
    const int j2 = t;
    float acc0 = b2[j2], acc1 = b2[j2];
    for (int k = 0; k < 128; ++k) {
        const float w2 = W2[k * 256 + j2];
        acc0 += h[0][k] * w2;
        acc1 += h[1][k] * w2;
    }
    if (j2 < 128) {
        ws[WS_FS + j2]       = 1.0f + acc0;
        ws[WS_FS + 128 + j2] = 1.0f + acc1;
    } else {
        ws[WS_SH + (j2 - 128)]       = acc0;
        ws[WS_SH + 128 + (j2 - 128)] = acc1;
    }
}

// ---------------------------------------------------------------------------
// k1: BARRIER-FREE accumulation pass (round-8, proven). Unchanged.
// ---------------------------------------------------------------------------
__global__ __launch_bounds__(256, 3) void k1_accum(
    const float* __restrict__ P, const int* __restrict__ mask,
    const float* __restrict__ Wg, const float* __restrict__ bg,
    const float* __restrict__ Wv, const float* __restrict__ bv,
    float* __restrict__ ws)
{
    __shared__ float red[4][1024];   // per-wave V' image [d*32+e]
    __shared__ float red_s[4][32];   // per-wave S image

    const int t  = threadIdx.x;
    const int b  = blockIdx.y;
    const int w  = t >> 6;
    const int l  = t & 63;
    const int lr = l & 15;
    const int lg = l >> 4;

    bf16x8 wfrag[2][2][4];
    #pragma unroll
    for (int nt = 0; nt < 2; ++nt)
      #pragma unroll
      for (int ks = 0; ks < 4; ++ks) {
        const int base = (ks * 32 + 8 * lg) * 32 + nt * 16 + lr;
        bf16x8 f0, f1;
        #pragma unroll
        for (int i = 0; i < 8; ++i) {
            f0[i] = (__bf16)Wg[base + i * 32];
            f1[i] = (__bf16)Wv[base + i * 32];
        }
        wfrag[0][nt][ks] = f0;
        wfrag[1][nt][ks] = f1;
      }
    const float bgv[2] = { bg[lr], bg[lr + 16] };
    const float bvv[2] = { bv[lr], bv[lr + 16] };

    f32x4 vq00 = {0,0,0,0}, vq01 = {0,0,0,0}, vq10 = {0,0,0,0}, vq11 = {0,0,0,0};
    float s0 = 0.f, s1 = 0.f;   // lane-partial S for d=lr / d=lr+16

    const float* Pb = P + (size_t)b * N2 * CC;
    const int*   mb = mask + (size_t)b * N2;

    for (int tile = blockIdx.x; tile < TILES; tile += gridDim.x) {
        const int row0 = tile * 64 + w * 16;
        const float* prow = Pb + (size_t)(row0 + lr) * CC + 8 * lg;

        bf16x8 afrag[4];
        #pragma unroll
        for (int ks = 0; ks < 4; ++ks) {
            const float4 a0 = *(const float4*)(prow + ks * 32);
            const float4 a1 = *(const float4*)(prow + ks * 32 + 4);
            bf16x8 f;
            f[0] = (__bf16)a0.x; f[1] = (__bf16)a0.y; f[2] = (__bf16)a0.z; f[3] = (__bf16)a0.w;
            f[4] = (__bf16)a1.x; f[5] = (__bf16)a1.y; f[6] = (__bf16)a1.z; f[7] = (__bf16)a1.w;
            afrag[ks] = f;
        }

        f32x4 facc0 = {0,0,0,0}, facc1 = {0,0,0,0}, gacc0 = {0,0,0,0}, gacc1 = {0,0,0,0};
        #pragma unroll
        for (int ks = 0; ks < 4; ++ks) {
            facc0 = MFMA16(afrag[ks], wfrag[0][0][ks], facc0);
            facc1 = MFMA16(afrag[ks], wfrag[0][1][ks], facc1);
            gacc0 = MFMA16(afrag[ks], wfrag[1][0][ks], gacc0);
            gacc1 = MFMA16(afrag[ks], wfrag[1][1][ks], gacc1);
        }

        const int4 mk4 = *(const int4*)&mb[row0 + lg * 4];
        const int mk[4] = { mk4.x, mk4.y, mk4.z, mk4.w };

        bf16x4 pe0, pe1, pg0, pg1;
        #pragma unroll
        for (int r = 0; r < 4; ++r) {
            pe0[r] = (__bf16)(mk[r] ? __expf(facc0[r] + bgv[0]) : 0.0f);
            pe1[r] = (__bf16)(mk[r] ? __expf(facc1[r] + bgv[1]) : 0.0f);
            pg0[r] = (__bf16)(gacc0[r] + bvv[0]);
            pg1[r] = (__bf16)(gacc1[r] + bvv[1]);
        }

        #pragma unroll
        for (int r = 0; r < 4; ++r) {
            s0 += (float)pe0[r];
            s1 += (float)pe1[r];
        }

        vq00 = mfma_k16(pe0, pg0, vq00);
        vq01 = mfma_k16(pe0, pg1, vq01);
        vq10 = mfma_k16(pe1, pg0, vq10);
        vq11 = mfma_k16(pe1, pg1, vq11);
    }

    s0 += __shfl_xor(s0, 16); s0 += __shfl_xor(s0, 32);
    s1 += __shfl_xor(s1, 16); s1 += __shfl_xor(s1, 32);

    #pragma unroll
    for (int r = 0; r < 4; ++r) {
        red[w][(     4 * lg + r) * 32 +      lr] = vq00[r];
        red[w][(     4 * lg + r) * 32 + 16 + lr] = vq01[r];
        red[w][(16 + 4 * lg + r) * 32 +      lr] = vq10[r];
        red[w][(16 + 4 * lg + r) * 32 + 16 + lr] = vq11[r];
    }
    if (lg == 0) { red_s[w][lr] = s0; red_s[w][16 + lr] = s1; }
    __syncthreads();

    #pragma unroll
    for (int i = 0; i < 4; ++i) {
        const int idx = t + i * 256;
        const float v = red[0][idx] + red[1][idx] + red[2][idx] + red[3][idx];
        atomicAdd(ws + WS_VACC + b * 1024 + idx, v);
    }
    if (t < 32) {
        const float sv = red_s[0][t] + red_s[1][t] + red_s[2][t] + red_s[3][t];
        atomicAdd(ws + WS_S + b * 32 + t, sv);
    }
}

// ---------------------------------------------------------------------------
// k2_mid: 2 blocks (one per batch). V-normalize, U' = V@Wo (fp32, staged Wo
// in LDS), scale by fs, write U' PRE-PACKED as bf16 MFMA A-frags + b2'.
// ---------------------------------------------------------------------------
__global__ __launch_bounds__(256) void k2_mid(
    const float* __restrict__ Wo, const float* __restrict__ bo,
    float* __restrict__ ws)
{
    __shared__ float V[1024];        // [d][e]
    __shared__ float wo[32][128];
    __shared__ float fs[128];
    const int t = threadIdx.x, b = blockIdx.x;

    if (t < 128) fs[t] = ws[WS_FS + b * 128 + t];
    #pragma unroll
    for (int i = 0; i < 4; ++i) {
        const int idx = t + i * 256;            // d*32+e
        const int d = idx >> 5;
        const float s = ws[WS_S + b * 32 + d];
        V[idx] = ws[WS_VACC + b * 1024 + idx] / (s * (1.0f + 1e-8f));
    }
    #pragma unroll
    for (int i = 0; i < 4; ++i) {
        const int j = t + i * 256;              // 1024 float4 = 4096 floats
        ((float4*)&wo[0][0])[j] = ((const float4*)Wo)[j];
    }
    __syncthreads();

    const int c = t & 127, dh = t >> 7;
    float wcol[32];
    #pragma unroll
    for (int e = 0; e < 32; ++e) wcol[e] = wo[e][c];
    const float fsc = fs[c];
    if (dh == 0) ws[WS_B2P + b * 128 + c] = bo[c] * fsc + ws[WS_SH + b * 128 + c];

    __bf16* dst = (__bf16*)(ws + WS_UPACK);
    #pragma unroll
    for (int dd = 0; dd < 16; ++dd) {
        const int d = dh * 16 + dd;
        float acc = 0.0f;
        #pragma unroll
        for (int e = 0; e < 32; ++e) acc += V[d * 32 + e] * wcol[e];
        acc *= fsc;
        // pack for lane l=(lg*16+lr): ufrag[nt][i] = U'[8*lg+i][nt*16+lr]
        const int lg = d >> 3, ii = d & 7, nt = c >> 4, lr = c & 15;
        dst[(((size_t)b * 8 + nt) * 64 + (lg * 16 + lr)) * 8 + ii] = (__bf16)acc;
    }
}

// ---------------------------------------------------------------------------
// k3: DUAL-TILE interleave. Each iteration processes two independent tiles
// (tA, tB=tA-1) with duplicated, source-interleaved chains: chain-B's
// issues hide chain-A's MFMA/softmax/LDS latencies and vice versa; ~2x
// outstanding loads per wave. No launch-bounds change (r3/r11: any
// tightening -> 64-VGPR notch + spill). LDS 10 KB (two h_t buffers).
// Grid 576x2: each block = 2 iterations x 2 adjacent tiles, reversed order.
// Tripwires: VGPR 110-150 (not 64), WRITE == 147456 KB, FETCH <= ~100 MB.
// ---------------------------------------------------------------------------
__global__ __launch_bounds__(256, 3) void k3_out(
    const float* __restrict__ P,
    const float* __restrict__ Wd, const float* __restrict__ bd,
    const float* __restrict__ ws, float* __restrict__ out)
{
    __shared__ __bf16 h_t[2][64][40];   // [tile-slot][wave-row][d]

    const int t  = threadIdx.x;
    const int b  = blockIdx.y;
    const int w  = t >> 6, l = t & 63, lr = l & 15, lg = l >> 4;

    // packed U' frags: 8 x 16B loads
    bf16x8 ufrag[8];
    {
        const bf16x8* up = (const bf16x8*)(ws + WS_UPACK) + (size_t)b * 512 + l;
        #pragma unroll
        for (int nt = 0; nt < 8; ++nt) ufrag[nt] = up[nt * 64];
    }
    // b2' per c-tile
    float b2v[8][4];
    #pragma unroll
    for (int nt = 0; nt < 8; ++nt) {
        const float4 v = *(const float4*)(ws + WS_B2P + b * 128 + nt * 16 + lg * 4);
        b2v[nt][0] = v.x; b2v[nt][1] = v.y; b2v[nt][2] = v.z; b2v[nt][3] = v.w;
    }
    // Wd frags (L2-broadcast)
    bf16x8 wdfrag[2][4];
    #pragma unroll
    for (int nt = 0; nt < 2; ++nt)
      #pragma unroll
      for (int ks = 0; ks < 4; ++ks) {
        const int base = (ks * 32 + 8 * lg) * 32 + nt * 16 + lr;
        bf16x8 f;
        #pragma unroll
        for (int i = 0; i < 8; ++i) f[i] = (__bf16)Wd[base + i * 32];
        wdfrag[nt][ks] = f;
      }
    float bdv[8];
    #pragma unroll
    for (int r = 0; r < 4; ++r) {
        bdv[r]     = bd[lg * 4 + r];
        bdv[4 + r] = bd[16 + lg * 4 + r];
    }

    const float* Pb = P + (size_t)b * N2 * CC;
    float*       Ob = out + (size_t)b * N2 * CC;

    for (int tile = TILES - 1 - 2 * blockIdx.x; tile >= 1; tile -= 2 * gridDim.x) {
        const int tB = tile - 1;
        const size_t rbaseA = (size_t)(tile * 64 + w * 16 + lr) * CC;
        const size_t rbaseB = (size_t)(tB   * 64 + w * 16 + lr) * CC;
        const float* prowA = Pb + rbaseA + 8 * lg;
        const float* prowB = Pb + rbaseB + 8 * lg;

        // ---- loads (both tiles) -> bf16 frags ----
        bf16x8 afragA[4], afragB[4];
        #pragma unroll
        for (int ks = 0; ks < 4; ++ks) {
            const float4 a0 = *(const float4*)(prowA + ks * 32);
            const float4 a1 = *(const float4*)(prowA + ks * 32 + 4);
            const float4 c0 = *(const float4*)(prowB + ks * 32);
            const float4 c1 = *(const float4*)(prowB + ks * 32 + 4);
            bf16x8 fa, fb;
            fa[0] = (__bf16)a0.x; fa[1] = (__bf16)a0.y; fa[2] = (__bf16)a0.z; fa[3] = (__bf16)a0.w;
            fa[4] = (__bf16)a1.x; fa[5] = (__bf16)a1.y; fa[6] = (__bf16)a1.z; fa[7] = (__bf16)a1.w;
            fb[0] = (__bf16)c0.x; fb[1] = (__bf16)c0.y; fb[2] = (__bf16)c0.z; fb[3] = (__bf16)c0.w;
            fb[4] = (__bf16)c1.x; fb[5] = (__bf16)c1.y; fb[6] = (__bf16)c1.z; fb[7] = (__bf16)c1.w;
            afragA[ks] = fa;
            afragB[ks] = fb;
        }

        // ---- T^T projections, A/B interleaved ----
        f32x4 dacc0A = {0,0,0,0}, dacc1A = {0,0,0,0};
        f32x4 dacc0B = {0,0,0,0}, dacc1B = {0,0,0,0};
        #pragma unroll
        for (int ks = 0; ks < 4; ++ks) {
            dacc0A = MFMA16(wdfrag[0][ks], afragA[ks], dacc0A);
            dacc0B = MFMA16(wdfrag[0][ks], afragB[ks], dacc0B);
            dacc1A = MFMA16(wdfrag[1][ks], afragA[ks], dacc1A);
            dacc1B = MFMA16(wdfrag[1][ks], afragB[ks], dacc1B);
        }

        // ---- softmax over d=32, two independent chains ----
        float vA[8], vB[8];
        #pragma unroll
        for (int r = 0; r < 4; ++r) {
            vA[r]     = dacc0A[r] + bdv[r];
            vA[4 + r] = dacc1A[r] + bdv[4 + r];
            vB[r]     = dacc0B[r] + bdv[r];
            vB[4 + r] = dacc1B[r] + bdv[4 + r];
        }
        float mA = vA[0], mB = vB[0];
        #pragma unroll
        for (int j = 1; j < 8; ++j) { mA = fmaxf(mA, vA[j]); mB = fmaxf(mB, vB[j]); }
        mA = fmaxf(mA, __shfl_xor(mA, 16));
        mB = fmaxf(mB, __shfl_xor(mB, 16));
        mA = fmaxf(mA, __shfl_xor(mA, 32));
        mB = fmaxf(mB, __shfl_xor(mB, 32));
        float eA[8], eB[8], sA = 0.f, sB = 0.f;
        #pragma unroll
        for (int j = 0; j < 8; ++j) {
            eA[j] = __expf(vA[j] - mA); sA += eA[j];
            eB[j] = __expf(vB[j] - mB); sB += eB[j];
        }
        sA += __shfl_xor(sA, 16); sB += __shfl_xor(sB, 16);
        sA += __shfl_xor(sA, 32); sB += __shfl_xor(sB, 32);
        const float invA = 1.0f / sA, invB = 1.0f / sB;

        bf16x4 h0A, h1A, h0B, h1B;
        #pragma unroll
        for (int r = 0; r < 4; ++r) {
            h0A[r] = (__bf16)(eA[r] * invA);
            h1A[r] = (__bf16)(eA[4 + r] * invA);
            h0B[r] = (__bf16)(eB[r] * invB);
            h1B[r] = (__bf16)(eB[4 + r] * invB);
        }
        const int hrow = w * 16 + lr;
        *(bf16x4*)&h_t[0][hrow][lg * 4]      = h0A;
        *(bf16x4*)&h_t[0][hrow][16 + lg * 4] = h1A;
        *(bf16x4*)&h_t[1][hrow][lg * 4]      = h0B;
        *(bf16x4*)&h_t[1][hrow][16 + lg * 4] = h1B;
        // wave-private rows: whole-wave DS ordering, no barrier needed
        const bf16x8 hfA = *(const bf16x8*)&h_t[0][hrow][8 * lg];
        const bf16x8 hfB = *(const bf16x8*)&h_t[1][hrow][8 * lg];

        // ---- epilogues: O^T per c-tile, A then B (independent streams) ----
        #pragma unroll
        for (int nt = 0; nt < 8; ++nt) {
            f32x4 ci;
            ci[0] = b2v[nt][0]; ci[1] = b2v[nt][1]; ci[2] = b2v[nt][2]; ci[3] = b2v[nt][3];
            const f32x4 oacc = MFMA16(ufrag[nt], hfA, ci);
            const size_t off = rbaseA + nt * 16 + lg * 4;
            const float4 p4 = *(const float4*)(Pb + off);
            float4 o4;
            o4.x = p4.x + oacc[0]; o4.y = p4.y + oacc[1];
            o4.z = p4.z + oacc[2]; o4.w = p4.w + oacc[3];
            *(float4*)(Ob + off) = o4;
        }
        #pragma unroll
        for (int nt = 0; nt < 8; ++nt) {
            f32x4 ci;
            ci[0] = b2v[nt][0]; ci[1] = b2v[nt][1]; ci[2] = b2v[nt][2]; ci[3] = b2v[nt][3];
            const f32x4 oacc = MFMA16(ufrag[nt], hfB, ci);
            const size_t off = rbaseB + nt * 16 + lg * 4;
            const float4 p4 = *(const float4*)(Pb + off);
            float4 o4;
            o4.x = p4.x + oacc[0]; o4.y = p4.y + oacc[1];
            o4.z = p4.z + oacc[2]; o4.w = p4.w + oacc[3];
            *(float4*)(Ob + off) = o4;
        }
    }
}

extern "C" void kernel_launch(void* const* d_in, const int* in_sizes, int n_in,
                              void* d_out, int out_size, void* d_ws, size_t ws_size,
                              hipStream_t stream) {
    const float* P   = (const float*)d_in[0];
    const int*   msk = (const int*)d_in[1];
    const float* r3t = (const float*)d_in[2];
    const float* Wg  = (const float*)d_in[3];
    const float* bg  = (const float*)d_in[4];
    const float* Wv  = (const float*)d_in[5];
    const float* bv  = (const float*)d_in[6];
    const float* Wd  = (const float*)d_in[7];
    const float* bd  = (const float*)d_in[8];
    const float* Wo  = (const float*)d_in[9];
    const float* bo  = (const float*)d_in[10];
    const float* W1  = (const float*)d_in[11];
    const float* b1  = (const float*)d_in[12];
    const float* W2  = (const float*)d_in[13];
    const float* b2  = (const float*)d_in[14];
    float* ws  = (float*)d_ws;
    float* out = (float*)d_out;

    hipLaunchKernelGGL(k0_init,  dim3(10),      dim3(256), 0, stream, r3t, W1, b1, W2, b2, ws);
    hipLaunchKernelGGL(k1_accum, dim3(384, 2),  dim3(256), 0, stream, P, msk, Wg, bg, Wv, bv, ws);
    hipLaunchKernelGGL(k2_mid,   dim3(2),       dim3(256), 0, stream, Wo, bo, ws);
    hipLaunchKernelGGL(k3_out,   dim3(576, 2),  dim3(256), 0, stream, P, Wd, bd, ws, out);
}

// Round 13
// 110.925 us; speedup vs baseline: 1.3279x; 1.1809x over previous
//
#include <hip/hip_runtime.h>
#include <hip/hip_bf16.h>
#include <math.h>

#define N2 147456
#define CC 128
#define TILES 2304   // N2/64

// workspace float offsets
#define WS_VACC  0      // [2][32][32]
#define WS_S     2048   // [2][32]
#define WS_FS    2112   // [2][128]  FiLM scale (1+scale)
#define WS_SH    2368   // [2][128]  FiLM shift
#define WS_UPACK 2624   // [2][8][64][8] bf16 = 16 KB = 4096 floats (packed ufrag)
#define WS_B2P   6720   // [2][128]  b2' = bo*fs + shift

typedef __attribute__((ext_vector_type(8))) __bf16 bf16x8;
typedef __attribute__((ext_vector_type(4))) __bf16 bf16x4;
typedef __attribute__((ext_vector_type(4))) float f32x4;
typedef __attribute__((ext_vector_type(4))) short short4v;

#define MFMA16(a_, b_, c_) __builtin_amdgcn_mfma_f32_16x16x32_bf16((a_), (b_), (c_), 0, 0, 0)

// 16x16x16 bf16 MFMA (K=16): carried-forward shape on gfx950 (ISA §10).
// Builtin name varies across ROCm versions -> __has_builtin chain.
static __device__ inline f32x4 mfma_k16(bf16x4 a, bf16x4 b, f32x4 c) {
#if __has_builtin(__builtin_amdgcn_mfma_f32_16x16x16_bf16)
    return __builtin_amdgcn_mfma_f32_16x16x16_bf16(a, b, c, 0, 0, 0);
#elif __has_builtin(__builtin_amdgcn_mfma_f32_16x16x16bf16_1k)
    return __builtin_amdgcn_mfma_f32_16x16x16bf16_1k(
        __builtin_bit_cast(short4v, a), __builtin_bit_cast(short4v, b), c, 0, 0, 0);
#else
    asm("v_mfma_f32_16x16x16_bf16 %0, %1, %2, %0" : "+v"(c) : "v"(a), "v"(b));
    return c;
#endif
}

// ---------------------------------------------------------------------------
// k0: zero accumulators (blocks 1..9) + FiLM time-MLP (block 0).
// ---------------------------------------------------------------------------
__global__ __launch_bounds__(256) void k0_init(
    const float* __restrict__ r3t,
    const float* __restrict__ W1, const float* __restrict__ b1,
    const float* __restrict__ W2, const float* __restrict__ b2,
    float* __restrict__ ws)
{
    const int t = threadIdx.x, bx = blockIdx.x;
    if (bx > 0) {
        const int i = (bx - 1) * 256 + t;
        if (i < 2112) ws[i] = 0.0f;
        return;
    }
    __shared__ float h[2][128];
    {
        const int b = t >> 7, j = t & 127;
        const float x = r3t[b] * W1[j] + b1[j];
        h[b][j] = 0.5f * x * (1.0f + erff(x * 0.7071067811865475f));
    }
    __syncthreads();
    const int j2 = t;
    float acc0 = b2[j2], acc1 = b2[j2];
    for (int k = 0; k < 128; ++k) {
        const float w2 = W2[k * 256 + j2];
        acc0 += h[0][k] * w2;
        acc1 += h[1][k] * w2;
    }
    if (j2 < 128) {
        ws[WS_FS + j2]       = 1.0f + acc0;
        ws[WS_FS + 128 + j2] = 1.0f + acc1;
    } else {
        ws[WS_SH + (j2 - 128)]       = acc0;
        ws[WS_SH + 128 + (j2 - 128)] = acc1;
    }
}

// ---------------------------------------------------------------------------
// k1: BARRIER-FREE accumulation pass.
// Key identity: the proj MFMA C/D layout (lane -> row=4*lg+r, col=lr) read
// as TRANSPOSED data is exactly the A/B fragment layout of the 16x16x16
// MFMA (lane -> m=lr, k=4*lg+i). So each wave computes its private 16-row
// contribution to all 4 quadrants of V' = EF^T @ GV straight from pe/pg
// registers: no LDS staging, no __syncthreads in the loop. S = col-sum(EF)
// becomes an in-lane accumulation of the SAME rounded bf16 values (order
// change only; atomicAdd order was already undefined). One barrier per
// kernel for the cross-wave reduction.
// ---------------------------------------------------------------------------
__global__ __launch_bounds__(256, 3) void k1_accum(
    const float* __restrict__ P, const int* __restrict__ mask,
    const float* __restrict__ Wg, const float* __restrict__ bg,
    const float* __restrict__ Wv, const float* __restrict__ bv,
    float* __restrict__ ws)
{
    __shared__ float red[4][1024];   // per-wave V' image [d*32+e]
    __shared__ float red_s[4][32];   // per-wave S image

    const int t  = threadIdx.x;
    const int b  = blockIdx.y;
    const int w  = t >> 6;
    const int l  = t & 63;
    const int lr = l & 15;
    const int lg = l >> 4;

    bf16x8 wfrag[2][2][4];
    #pragma unroll
    for (int nt = 0; nt < 2; ++nt)
      #pragma unroll
      for (int ks = 0; ks < 4; ++ks) {
        const int base = (ks * 32 + 8 * lg) * 32 + nt * 16 + lr;
        bf16x8 f0, f1;
        #pragma unroll
        for (int i = 0; i < 8; ++i) {
            f0[i] = (__bf16)Wg[base + i * 32];
            f1[i] = (__bf16)Wv[base + i * 32];
        }
        wfrag[0][nt][ks] = f0;
        wfrag[1][nt][ks] = f1;
      }
    const float bgv[2] = { bg[lr], bg[lr + 16] };
    const float bvv[2] = { bv[lr], bv[lr + 16] };

    f32x4 vq00 = {0,0,0,0}, vq01 = {0,0,0,0}, vq10 = {0,0,0,0}, vq11 = {0,0,0,0};
    float s0 = 0.f, s1 = 0.f;   // lane-partial S for d=lr / d=lr+16

    const float* Pb = P + (size_t)b * N2 * CC;
    const int*   mb = mask + (size_t)b * N2;

    for (int tile = blockIdx.x; tile < TILES; tile += gridDim.x) {
        const int row0 = tile * 64 + w * 16;
        const float* prow = Pb + (size_t)(row0 + lr) * CC + 8 * lg;

        bf16x8 afrag[4];
        #pragma unroll
        for (int ks = 0; ks < 4; ++ks) {
            const float4 a0 = *(const float4*)(prow + ks * 32);
            const float4 a1 = *(const float4*)(prow + ks * 32 + 4);
            bf16x8 f;
            f[0] = (__bf16)a0.x; f[1] = (__bf16)a0.y; f[2] = (__bf16)a0.z; f[3] = (__bf16)a0.w;
            f[4] = (__bf16)a1.x; f[5] = (__bf16)a1.y; f[6] = (__bf16)a1.z; f[7] = (__bf16)a1.w;
            afrag[ks] = f;
        }

        f32x4 facc0 = {0,0,0,0}, facc1 = {0,0,0,0}, gacc0 = {0,0,0,0}, gacc1 = {0,0,0,0};
        #pragma unroll
        for (int ks = 0; ks < 4; ++ks) {
            facc0 = MFMA16(afrag[ks], wfrag[0][0][ks], facc0);
            facc1 = MFMA16(afrag[ks], wfrag[0][1][ks], facc1);
            gacc0 = MFMA16(afrag[ks], wfrag[1][0][ks], gacc0);
            gacc1 = MFMA16(afrag[ks], wfrag[1][1][ks], gacc1);
        }

        const int4 mk4 = *(const int4*)&mb[row0 + lg * 4];
        const int mk[4] = { mk4.x, mk4.y, mk4.z, mk4.w };

        bf16x4 pe0, pe1, pg0, pg1;
        #pragma unroll
        for (int r = 0; r < 4; ++r) {
            pe0[r] = (__bf16)(mk[r] ? __expf(facc0[r] + bgv[0]) : 0.0f);
            pe1[r] = (__bf16)(mk[r] ? __expf(facc1[r] + bgv[1]) : 0.0f);
            pg0[r] = (__bf16)(gacc0[r] + bvv[0]);
            pg1[r] = (__bf16)(gacc1[r] + bvv[1]);
        }

        // S partials: sum the ROUNDED bf16 values (same data as before)
        #pragma unroll
        for (int r = 0; r < 4; ++r) {
            s0 += (float)pe0[r];
            s1 += (float)pe1[r];
        }

        // V' quadrants: EF^T @ GV over this wave's 16 rows (K=16)
        vq00 = mfma_k16(pe0, pg0, vq00);
        vq01 = mfma_k16(pe0, pg1, vq01);
        vq10 = mfma_k16(pe1, pg0, vq10);
        vq11 = mfma_k16(pe1, pg1, vq11);
    }

    // reduce S across lg groups (rows) within the wave
    s0 += __shfl_xor(s0, 16); s0 += __shfl_xor(s0, 32);
    s1 += __shfl_xor(s1, 16); s1 += __shfl_xor(s1, 32);

    // stage per-wave images; quadrant (i,j): lane holds V'[i*16+4*lg+r][j*16+lr]
    #pragma unroll
    for (int r = 0; r < 4; ++r) {
        red[w][(     4 * lg + r) * 32 +      lr] = vq00[r];
        red[w][(     4 * lg + r) * 32 + 16 + lr] = vq01[r];
        red[w][(16 + 4 * lg + r) * 32 +      lr] = vq10[r];
        red[w][(16 + 4 * lg + r) * 32 + 16 + lr] = vq11[r];
    }
    if (lg == 0) { red_s[w][lr] = s0; red_s[w][16 + lr] = s1; }
    __syncthreads();

    #pragma unroll
    for (int i = 0; i < 4; ++i) {
        const int idx = t + i * 256;
        const float v = red[0][idx] + red[1][idx] + red[2][idx] + red[3][idx];
        atomicAdd(ws + WS_VACC + b * 1024 + idx, v);
    }
    if (t < 32) {
        const float sv = red_s[0][t] + red_s[1][t] + red_s[2][t] + red_s[3][t];
        atomicAdd(ws + WS_S + b * 32 + t, sv);
    }
}

// ---------------------------------------------------------------------------
// k2_mid: 2 blocks (one per batch). V-normalize, U' = V@Wo (fp32, staged Wo
// in LDS), scale by fs, write U' PRE-PACKED as bf16 MFMA A-frags + b2'.
// ---------------------------------------------------------------------------
__global__ __launch_bounds__(256) void k2_mid(
    const float* __restrict__ Wo, const float* __restrict__ bo,
    float* __restrict__ ws)
{
    __shared__ float V[1024];        // [d][e]
    __shared__ float wo[32][128];
    __shared__ float fs[128];
    const int t = threadIdx.x, b = blockIdx.x;

    if (t < 128) fs[t] = ws[WS_FS + b * 128 + t];
    #pragma unroll
    for (int i = 0; i < 4; ++i) {
        const int idx = t + i * 256;            // d*32+e
        const int d = idx >> 5;
        const float s = ws[WS_S + b * 32 + d];
        V[idx] = ws[WS_VACC + b * 1024 + idx] / (s * (1.0f + 1e-8f));
    }
    #pragma unroll
    for (int i = 0; i < 4; ++i) {
        const int j = t + i * 256;              // 1024 float4 = 4096 floats
        ((float4*)&wo[0][0])[j] = ((const float4*)Wo)[j];
    }
    __syncthreads();

    const int c = t & 127, dh = t >> 7;
    float wcol[32];
    #pragma unroll
    for (int e = 0; e < 32; ++e) wcol[e] = wo[e][c];
    const float fsc = fs[c];
    if (dh == 0) ws[WS_B2P + b * 128 + c] = bo[c] * fsc + ws[WS_SH + b * 128 + c];

    __bf16* dst = (__bf16*)(ws + WS_UPACK);
    #pragma unroll
    for (int dd = 0; dd < 16; ++dd) {
        const int d = dh * 16 + dd;
        float acc = 0.0f;
        #pragma unroll
        for (int e = 0; e < 32; ++e) acc += V[d * 32 + e] * wcol[e];
        acc *= fsc;
        // pack for lane l=(lg*16+lr): ufrag[nt][i] = U'[8*lg+i][nt*16+lr]
        const int lg = d >> 3, ii = d & 7, nt = c >> 4, lr = c & 15;
        dst[(((size_t)b * 8 + nt) * 64 + (lg * 16 + lr)) * 8 + ii] = (__bf16)acc;
    }
}

// ---------------------------------------------------------------------------
// k3: EXACT round-4/8 body and grid (proven 68us: slim prologue, transposed-
// MFMA, reversed tiles, LATE p4 residual loads = L1 hits, FETCH 74MB).
// Closed after 6 negative/neutral experiments: grid size (r7 neutral),
// cross-tile prefetch (r6 -17us), in-tile hoist (r9 neutral), launch-bounds
// tightening (r3/r11 spill to 64-VGPR notch), dual-tile ILP (r12 -20us),
// producer-side hP fusion (r5/r10 -10/-24us). Latency-structural at ~68us.
// ---------------------------------------------------------------------------
__global__ __launch_bounds__(256, 3) void k3_out(
    const float* __restrict__ P,
    const float* __restrict__ Wd, const float* __restrict__ bd,
    const float* __restrict__ ws, float* __restrict__ out)
{
    __shared__ __bf16 h_t[64][40];   // [wave-row][d], stride 40 el = 16B-aligned

    const int t  = threadIdx.x;
    const int b  = blockIdx.y;
    const int w  = t >> 6, l = t & 63, lr = l & 15, lg = l >> 4;

    // packed U' frags: 8 x 16B loads
    bf16x8 ufrag[8];
    {
        const bf16x8* up = (const bf16x8*)(ws + WS_UPACK) + (size_t)b * 512 + l;
        #pragma unroll
        for (int nt = 0; nt < 8; ++nt) ufrag[nt] = up[nt * 64];
    }
    // b2' per c-tile
    float b2v[8][4];
    #pragma unroll
    for (int nt = 0; nt < 8; ++nt) {
        const float4 v = *(const float4*)(ws + WS_B2P + b * 128 + nt * 16 + lg * 4);
        b2v[nt][0] = v.x; b2v[nt][1] = v.y; b2v[nt][2] = v.z; b2v[nt][3] = v.w;
    }
    // Wd frags (L2-broadcast)
    bf16x8 wdfrag[2][4];
    #pragma unroll
    for (int nt = 0; nt < 2; ++nt)
      #pragma unroll
      for (int ks = 0; ks < 4; ++ks) {
        const int base = (ks * 32 + 8 * lg) * 32 + nt * 16 + lr;
        bf16x8 f;
        #pragma unroll
        for (int i = 0; i < 8; ++i) f[i] = (__bf16)Wd[base + i * 32];
        wdfrag[nt][ks] = f;
      }
    float bdv[8];
    #pragma unroll
    for (int r = 0; r < 4; ++r) {
        bdv[r]     = bd[lg * 4 + r];
        bdv[4 + r] = bd[16 + lg * 4 + r];
    }

    const float* Pb = P + (size_t)b * N2 * CC;
    float*       Ob = out + (size_t)b * N2 * CC;

    for (int tile = TILES - 1 - blockIdx.x; tile >= 0; tile -= gridDim.x) {
        const int row0 = tile * 64 + w * 16;
        const size_t rbase = (size_t)(row0 + lr) * CC;
        const float* prow = Pb + rbase + 8 * lg;

        bf16x8 afrag[4];
        #pragma unroll
        for (int ks = 0; ks < 4; ++ks) {
            const float4 a0 = *(const float4*)(prow + ks * 32);
            const float4 a1 = *(const float4*)(prow + ks * 32 + 4);
            bf16x8 f;
            f[0] = (__bf16)a0.x; f[1] = (__bf16)a0.y; f[2] = (__bf16)a0.z; f[3] = (__bf16)a0.w;
            f[4] = (__bf16)a1.x; f[5] = (__bf16)a1.y; f[6] = (__bf16)a1.z; f[7] = (__bf16)a1.w;
            afrag[ks] = f;
        }

        // T^T: lane holds row=row0+lr, d = {lg*4+r, 16+lg*4+r}
        f32x4 dacc0 = {0,0,0,0}, dacc1 = {0,0,0,0};
        #pragma unroll
        for (int ks = 0; ks < 4; ++ks) {
            dacc0 = MFMA16(wdfrag[0][ks], afrag[ks], dacc0);
            dacc1 = MFMA16(wdfrag[1][ks], afrag[ks], dacc1);
        }

        float v[8];
        #pragma unroll
        for (int r = 0; r < 4; ++r) {
            v[r]     = dacc0[r] + bdv[r];
            v[4 + r] = dacc1[r] + bdv[4 + r];
        }
        // softmax over d=32: 8 in-lane + lanes {l^16, l^32}
        float m = v[0];
        #pragma unroll
        for (int j = 1; j < 8; ++j) m = fmaxf(m, v[j]);
        m = fmaxf(m, __shfl_xor(m, 16));
        m = fmaxf(m, __shfl_xor(m, 32));
        float e[8], s = 0.f;
        #pragma unroll
        for (int j = 0; j < 8; ++j) { e[j] = __expf(v[j] - m); s += e[j]; }
        s += __shfl_xor(s, 16);
        s += __shfl_xor(s, 32);
        const float inv = 1.0f / s;

        bf16x4 h0, h1;
        #pragma unroll
        for (int r = 0; r < 4; ++r) {
            h0[r] = (__bf16)(e[r] * inv);
            h1[r] = (__bf16)(e[4 + r] * inv);
        }
        const int hrow = w * 16 + lr;
        *(bf16x4*)&h_t[hrow][lg * 4]      = h0;
        *(bf16x4*)&h_t[hrow][16 + lg * 4] = h1;
        // wave-private rows: whole-wave DS ordering, no barrier needed
        const bf16x8 hf = *(const bf16x8*)&h_t[hrow][8 * lg];

        // O^T per c-tile: lane -> row=row0+lr, c = nt*16 + lg*4 + {0..3}
        #pragma unroll
        for (int nt = 0; nt < 8; ++nt) {
            f32x4 ci;
            ci[0] = b2v[nt][0]; ci[1] = b2v[nt][1]; ci[2] = b2v[nt][2]; ci[3] = b2v[nt][3];
            const f32x4 oacc = MFMA16(ufrag[nt], hf, ci);
            const size_t off = rbase + nt * 16 + lg * 4;
            const float4 p4 = *(const float4*)(Pb + off);
            float4 o4;
            o4.x = p4.x + oacc[0]; o4.y = p4.y + oacc[1];
            o4.z = p4.z + oacc[2]; o4.w = p4.w + oacc[3];
            *(float4*)(Ob + off) = o4;
        }
    }
}

extern "C" void kernel_launch(void* const* d_in, const int* in_sizes, int n_in,
                              void* d_out, int out_size, void* d_ws, size_t ws_size,
                              hipStream_t stream) {
    const float* P   = (const float*)d_in[0];
    const int*   msk = (const int*)d_in[1];
    const float* r3t = (const float*)d_in[2];
    const float* Wg  = (const float*)d_in[3];
    const float* bg  = (const float*)d_in[4];
    const float* Wv  = (const float*)d_in[5];
    const float* bv  = (const float*)d_in[6];
    const float* Wd  = (const float*)d_in[7];
    const float* bd  = (const float*)d_in[8];
    const float* Wo  = (const float*)d_in[9];
    const float* bo  = (const float*)d_in[10];
    const float* W1  = (const float*)d_in[11];
    const float* b1  = (const float*)d_in[12];
    const float* W2  = (const float*)d_in[13];
    const float* b2  = (const float*)d_in[14];
    float* ws  = (float*)d_ws;
    float* out = (float*)d_out;

    hipLaunchKernelGGL(k0_init,  dim3(10),      dim3(256), 0, stream, r3t, W1, b1, W2, b2, ws);
    hipLaunchKernelGGL(k1_accum, dim3(384, 2),  dim3(256), 0, stream, P, msk, Wg, bg, Wv, bv, ws);
    hipLaunchKernelGGL(k2_mid,   dim3(2),       dim3(256), 0, stream, Wo, bo, ws);
    hipLaunchKernelGGL(k3_out,   dim3(768, 2),  dim3(256), 0, stream, P, Wd, bd, ws, out);
}